// Round 4
// baseline (606.848 us; speedup 1.0000x reference)
//
#include <hip/hip_runtime.h>

#define N_NODES 100000
#define E_EDGES 1600000
#define CSR_CAP (E_EDGES + 4 * N_NODES)  // padded capacity

// ---------------- degree ----------------

__global__ void deg_kernel(const int* __restrict__ row, const int* __restrict__ col,
                           unsigned int* __restrict__ deg) {
    int e = blockIdx.x * blockDim.x + threadIdx.x;
    if (e >= E_EDGES) return;
    int r = row[e], c = col[e];
    if (r != c) atomicAdd(&deg[r], 1u);
}

// ---------------- scan of PADDED deg -> rowptr ; dis fused ----------------

__global__ void scan1_kernel(const unsigned int* __restrict__ deg,
                             unsigned int* __restrict__ rowptr,
                             unsigned int* __restrict__ bsum,
                             float* __restrict__ dis) {
    __shared__ unsigned int tmp[256];
    int i = blockIdx.x * 256 + threadIdx.x;
    unsigned int d = (i < N_NODES) ? deg[i] : 0u;
    if (i < N_NODES) dis[i] = (d > 0u) ? rsqrtf((float)d) : 0.0f;
    if (i == N_NODES) dis[i] = 0.0f;  // sentinel slot: zero weight for pads
    unsigned int v = (d + 3u) & ~3u;  // pad each row to multiple of 4
    tmp[threadIdx.x] = v;
    __syncthreads();
    for (int ofs = 1; ofs < 256; ofs <<= 1) {
        unsigned int t = (threadIdx.x >= ofs) ? tmp[threadIdx.x - ofs] : 0u;
        __syncthreads();
        tmp[threadIdx.x] += t;
        __syncthreads();
    }
    if (i < N_NODES) rowptr[i] = tmp[threadIdx.x] - v;  // local exclusive (padded)
    if (threadIdx.x == 255) bsum[blockIdx.x] = tmp[255];
}

__global__ void scan2_kernel(unsigned int* __restrict__ bsum, int nb) {
    __shared__ unsigned int tmp[512];
    unsigned int v = (threadIdx.x < nb) ? bsum[threadIdx.x] : 0u;
    tmp[threadIdx.x] = v;
    __syncthreads();
    for (int ofs = 1; ofs < 512; ofs <<= 1) {
        unsigned int t = (threadIdx.x >= ofs) ? tmp[threadIdx.x - ofs] : 0u;
        __syncthreads();
        tmp[threadIdx.x] += t;
        __syncthreads();
    }
    if (threadIdx.x < nb) bsum[threadIdx.x] = tmp[threadIdx.x] - v;  // exclusive
}

__global__ void scan3_kernel(unsigned int* __restrict__ rowptr,
                             const unsigned int* __restrict__ bsum,
                             unsigned int* __restrict__ cursor) {
    int i = blockIdx.x * 256 + threadIdx.x;
    if (i < N_NODES) {
        unsigned int v = rowptr[i] + bsum[blockIdx.x];
        rowptr[i] = v;
        cursor[i] = v;
    }
}

// ---------------- CSR fill: only column indices (weights factored out) ----------------

__global__ void fill_kernel(const int* __restrict__ row, const int* __restrict__ col,
                            unsigned int* __restrict__ cursor,
                            int* __restrict__ ccol) {
    int e = blockIdx.x * blockDim.x + threadIdx.x;
    if (e >= E_EDGES) return;
    int r = row[e], c = col[e];
    if (r == c) return;
    unsigned int pos = atomicAdd(&cursor[r], 1u);
    ccol[pos] = c;
}

// ---------------- SpMM 64-dim: (Lv)[r] = -dis[r] * sum dis[c] v[c] ----------------

__global__ void spmm64_kernel(const unsigned int* __restrict__ rowptr,
                              const unsigned int* __restrict__ deg,
                              const unsigned int* __restrict__ ccol,
                              const float* __restrict__ dis,
                              const float* __restrict__ vin, float* __restrict__ vout) {
    int wid = blockIdx.x * 4 + (threadIdx.x >> 6);
    int lane = threadIdx.x & 63;
    if (wid >= N_NODES) return;
    unsigned int s = rowptr[wid];
    int pd = (int)((deg[wid] + 3u) & ~3u);
    float a0 = 0.0f, a1 = 0.0f, a2 = 0.0f, a3 = 0.0f;
    for (int e = 0; e < pd; e += 4) {
        unsigned int c0 = ccol[s + e + 0];
        unsigned int c1 = ccol[s + e + 1];
        unsigned int c2 = ccol[s + e + 2];
        unsigned int c3 = ccol[s + e + 3];
        // pads are 0xFFFFFFFF: weight index clamps to N (dis[N]=0), addr clamps to N-1
        float w0 = dis[min(c0, (unsigned int)N_NODES)];
        float w1 = dis[min(c1, (unsigned int)N_NODES)];
        float w2 = dis[min(c2, (unsigned int)N_NODES)];
        float w3 = dis[min(c3, (unsigned int)N_NODES)];
        float v0 = vin[(size_t)min(c0, (unsigned int)(N_NODES - 1)) * 64 + lane];
        float v1 = vin[(size_t)min(c1, (unsigned int)(N_NODES - 1)) * 64 + lane];
        float v2 = vin[(size_t)min(c2, (unsigned int)(N_NODES - 1)) * 64 + lane];
        float v3 = vin[(size_t)min(c3, (unsigned int)(N_NODES - 1)) * 64 + lane];
        a0 += w0 * v0;
        a1 += w1 * v1;
        a2 += w2 * v2;
        a3 += w3 * v3;
    }
    vout[(size_t)wid * 64 + lane] = -dis[wid] * ((a0 + a1) + (a2 + a3));
}

// ---------------- SpMM 16-dim with fused epilogues ----------------
// MODE 0: vout = add + 2*(Lv)   MODE 1: vout = add + (Lv)

template <int MODE>
__global__ void spmm16_kernel(const unsigned int* __restrict__ rowptr,
                              const unsigned int* __restrict__ deg,
                              const unsigned int* __restrict__ ccol,
                              const float* __restrict__ dis,
                              const float* __restrict__ vin, const float* __restrict__ add,
                              float* __restrict__ vout) {
    int wid = blockIdx.x * 16 + (threadIdx.x >> 4);
    int l16 = threadIdx.x & 15;
    if (wid >= N_NODES) return;
    unsigned int s = rowptr[wid];
    int pd = (int)((deg[wid] + 3u) & ~3u);
    float a0 = 0.0f, a1 = 0.0f, a2 = 0.0f, a3 = 0.0f;
    for (int e = 0; e < pd; e += 4) {
        unsigned int c0 = ccol[s + e + 0];
        unsigned int c1 = ccol[s + e + 1];
        unsigned int c2 = ccol[s + e + 2];
        unsigned int c3 = ccol[s + e + 3];
        float w0 = dis[min(c0, (unsigned int)N_NODES)];
        float w1 = dis[min(c1, (unsigned int)N_NODES)];
        float w2 = dis[min(c2, (unsigned int)N_NODES)];
        float w3 = dis[min(c3, (unsigned int)N_NODES)];
        a0 += w0 * vin[(size_t)min(c0, (unsigned int)(N_NODES - 1)) * 16 + l16];
        a1 += w1 * vin[(size_t)min(c1, (unsigned int)(N_NODES - 1)) * 16 + l16];
        a2 += w2 * vin[(size_t)min(c2, (unsigned int)(N_NODES - 1)) * 16 + l16];
        a3 += w3 * vin[(size_t)min(c3, (unsigned int)(N_NODES - 1)) * 16 + l16];
    }
    float acc = (a0 + a1) + (a2 + a3);
    float scl = (MODE == 0) ? (-2.0f * dis[wid]) : (-dis[wid]);
    vout[(size_t)wid * 16 + l16] = add[(size_t)wid * 16 + l16] + scl * acc;
}

// ---------------- fused layer-1 GEMM + ReLU + layer-2 projection ----------------
// Phase 1: h[n][0:64] = relu(t0@W1_0 + t1@W1_1 + (2B - t0)@W1_2 + b1)   (h in LDS only)
// Phase 2: P = h@(W2_0 - W2_2) + b2, Q = h@W2_1, R = h@W2_2
// Block: 256 threads = 16 nodes x 16 j-groups (4 j each).

__global__ __launch_bounds__(256) void gemm_fused_kernel(
    const float* __restrict__ t0p, const float* __restrict__ t1p,
    const float* __restrict__ brawp,
    const float* __restrict__ W1, const float* __restrict__ b1,
    const float* __restrict__ W2, const float* __restrict__ b2,
    float* __restrict__ P, float* __restrict__ Q, float* __restrict__ R) {

    __shared__ float Hs[16][68];     // padded: 68%32=4 -> conflict-free broadcast reads
    __shared__ float Wp[64 * 48];    // transformed layer-2 weights [k][48]

    // stage Wp
    for (int i = threadIdx.x; i < 64 * 48; i += 256) {
        int k = i / 48, j = i % 48;
        float v;
        if (j < 16)      v = W2[k * 16 + j] - W2[2048 + k * 16 + j];
        else if (j < 32) v = W2[1024 + k * 16 + (j - 16)];
        else             v = W2[2048 + k * 16 + (j - 32)];
        Wp[i] = v;
    }

    int n_local = threadIdx.x >> 4;  // 0..15
    int jg = threadIdx.x & 15;       // 0..15
    int n = blockIdx.x * 16 + n_local;  // grid sized so n < N_NODES always

    float acc0 = 0.0f, acc1 = 0.0f, acc2 = 0.0f, acc3 = 0.0f;
    {
        const float4* x0 = (const float4*)(t0p + (size_t)n * 64);
        const float4* x1 = (const float4*)(t1p + (size_t)n * 64);
        const float4* xb = (const float4*)(brawp + (size_t)n * 64);
        const float4* w0p = (const float4*)(W1) + jg;
        const float4* w1p = (const float4*)(W1 + 4096) + jg;
        const float4* w2p = (const float4*)(W1 + 8192) + jg;
#pragma unroll 4
        for (int k4 = 0; k4 < 16; k4++) {
            float4 a0 = x0[k4], a1 = x1[k4], ab = xb[k4];
            float t0v[4] = {a0.x, a0.y, a0.z, a0.w};
            float t1v[4] = {a1.x, a1.y, a1.z, a1.w};
            float tbv[4] = {ab.x, ab.y, ab.z, ab.w};
#pragma unroll
            for (int kk = 0; kk < 4; kk++) {
                int k = k4 * 4 + kk;
                float t0 = t0v[kk], t1 = t1v[kk];
                float t2 = 2.0f * tbv[kk] - t0;
                float4 w0 = w0p[k * 16], w1 = w1p[k * 16], w2 = w2p[k * 16];
                acc0 += t0 * w0.x + t1 * w1.x + t2 * w2.x;
                acc1 += t0 * w0.y + t1 * w1.y + t2 * w2.y;
                acc2 += t0 * w0.z + t1 * w1.z + t2 * w2.z;
                acc3 += t0 * w0.w + t1 * w1.w + t2 * w2.w;
            }
        }
    }
    {
        float4 bb = ((const float4*)b1)[jg];
        float4 h;
        h.x = fmaxf(acc0 + bb.x, 0.0f);
        h.y = fmaxf(acc1 + bb.y, 0.0f);
        h.z = fmaxf(acc2 + bb.z, 0.0f);
        h.w = fmaxf(acc3 + bb.w, 0.0f);
        *(float4*)&Hs[n_local][jg * 4] = h;
    }
    __syncthreads();

    // phase 2: 12 active j-groups (48 outputs)
    if (jg < 12) {
        const float* hrow = &Hs[n_local][0];
        float p0 = 0.0f, p1 = 0.0f, p2 = 0.0f, p3 = 0.0f;
#pragma unroll 4
        for (int k = 0; k < 64; k++) {
            float hv = hrow[k];
            float4 w = *(const float4*)&Wp[k * 48 + jg * 4];
            p0 += hv * w.x;
            p1 += hv * w.y;
            p2 += hv * w.z;
            p3 += hv * w.w;
        }
        size_t base = (size_t)n * 16;
        if (jg < 4) {
            float4 bv = ((const float4*)b2)[jg];
            float4 ov = make_float4(p0 + bv.x, p1 + bv.y, p2 + bv.z, p3 + bv.w);
            ((float4*)(P + base))[jg] = ov;
        } else if (jg < 8) {
            ((float4*)(Q + base))[jg - 4] = make_float4(p0, p1, p2, p3);
        } else {
            ((float4*)(R + base))[jg - 8] = make_float4(p0, p1, p2, p3);
        }
    }
}

// ---------------- launch ----------------

extern "C" void kernel_launch(void* const* d_in, const int* in_sizes, int n_in,
                              void* d_out, int out_size, void* d_ws, size_t ws_size,
                              hipStream_t stream) {
    const float* x  = (const float*)d_in[0];
    const int* edge = (const int*)d_in[1];
    const float* W1 = (const float*)d_in[2];
    const float* b1 = (const float*)d_in[3];
    const float* W2 = (const float*)d_in[4];
    const float* b2 = (const float*)d_in[5];
    float* out = (float*)d_out;

    const int* row = edge;            // edge_index[0]
    const int* col = edge + E_EDGES;  // edge_index[1]

    // workspace layout
    char* ws = (char*)d_ws;
    size_t off = 0;
    auto alloc = [&](size_t bytes) {
        void* p = ws + off;
        off = (off + bytes + 255) & ~(size_t)255;
        return p;
    };
    unsigned int* deg    = (unsigned int*)alloc(N_NODES * 4);
    float*        dis    = (float*)alloc((N_NODES + 1) * 4);  // +1 sentinel (=0)
    unsigned int* rowptr = (unsigned int*)alloc(N_NODES * 4);
    unsigned int* cursor = (unsigned int*)alloc(N_NODES * 4);
    unsigned int* bsum   = (unsigned int*)alloc(512 * 4);
    unsigned int* ccol   = (unsigned int*)alloc((size_t)CSR_CAP * 4);
    float*        A      = (float*)alloc((size_t)N_NODES * 64 * 4);
    float*        B      = (float*)alloc((size_t)N_NODES * 64 * 4);
    float*        P      = (float*)alloc((size_t)N_NODES * 16 * 4);
    float*        Q      = (float*)alloc((size_t)N_NODES * 16 * 4);
    float*        R      = (float*)alloc((size_t)N_NODES * 16 * 4);
    float*        S      = (float*)alloc((size_t)N_NODES * 16 * 4);

    const int nodeBlocks   = (N_NODES + 255) / 256;  // 391
    const int edgeBlocks   = (E_EDGES + 255) / 256;  // 6250
    const int spmm64Blocks = (N_NODES + 3) / 4;      // 1 wave/row
    const int spmm16Blocks = (N_NODES + 15) / 16;    // 16 lanes/row
    const int gemmBlocks   = N_NODES / 16;           // 6250, exact

    // ---- build norm + padded CSR ----
    hipMemsetAsync(deg, 0, N_NODES * 4, stream);
    hipMemsetAsync(ccol, 0xFF, (size_t)CSR_CAP * 4, stream);  // pad sentinel
    deg_kernel<<<edgeBlocks, 256, 0, stream>>>(row, col, deg);
    scan1_kernel<<<nodeBlocks, 256, 0, stream>>>(deg, rowptr, bsum, dis);
    scan2_kernel<<<1, 512, 0, stream>>>(bsum, nodeBlocks);
    scan3_kernel<<<nodeBlocks, 256, 0, stream>>>(rowptr, bsum, cursor);
    fill_kernel<<<edgeBlocks, 256, 0, stream>>>(row, col, cursor, (int*)ccol);

    // ---- layer 1 SpMMs: A = Lx, B = LA ----
    spmm64_kernel<<<spmm64Blocks, 256, 0, stream>>>(rowptr, deg, ccol, dis, x, A);
    spmm64_kernel<<<spmm64Blocks, 256, 0, stream>>>(rowptr, deg, ccol, dis, A, B);

    // ---- fused GEMMs: h (LDS-only) -> P, Q, R ----
    gemm_fused_kernel<<<gemmBlocks, 256, 0, stream>>>(x, A, B, W1, b1, W2, b2, P, Q, R);

    // ---- layer 2 SpMMs: S = Q + 2*L(R); out = P + L(S) ----
    spmm16_kernel<0><<<spmm16Blocks, 256, 0, stream>>>(rowptr, deg, ccol, dis, R, Q, S);
    spmm16_kernel<1><<<spmm16Blocks, 256, 0, stream>>>(rowptr, deg, ccol, dis, S, P, out);
}

// Round 5
// 485.441 us; speedup vs baseline: 1.2501x; 1.2501x over previous
//
#include <hip/hip_runtime.h>

#define N_NODES 100000
#define E_EDGES 1600000
#define CSR_CAP (E_EDGES + 4 * N_NODES)  // padded capacity

// ---------------- degree ----------------

__global__ void deg_kernel(const int* __restrict__ row, const int* __restrict__ col,
                           unsigned int* __restrict__ deg) {
    int e = blockIdx.x * blockDim.x + threadIdx.x;
    if (e >= E_EDGES) return;
    int r = row[e], c = col[e];
    if (r != c) atomicAdd(&deg[r], 1u);
}

// ---------------- scan of PADDED deg -> rowptr ; dis fused ----------------

__global__ void scan1_kernel(const unsigned int* __restrict__ deg,
                             unsigned int* __restrict__ rowptr,
                             unsigned int* __restrict__ bsum,
                             float* __restrict__ dis) {
    __shared__ unsigned int tmp[256];
    int i = blockIdx.x * 256 + threadIdx.x;
    unsigned int d = (i < N_NODES) ? deg[i] : 0u;
    if (i < N_NODES) dis[i] = (d > 0u) ? rsqrtf((float)d) : 0.0f;
    if (i == N_NODES) dis[i] = 0.0f;  // sentinel slot: zero weight for pads
    unsigned int v = (d + 3u) & ~3u;  // pad each row to multiple of 4
    tmp[threadIdx.x] = v;
    __syncthreads();
    for (int ofs = 1; ofs < 256; ofs <<= 1) {
        unsigned int t = (threadIdx.x >= ofs) ? tmp[threadIdx.x - ofs] : 0u;
        __syncthreads();
        tmp[threadIdx.x] += t;
        __syncthreads();
    }
    if (i < N_NODES) rowptr[i] = tmp[threadIdx.x] - v;  // local exclusive (padded)
    if (threadIdx.x == 255) bsum[blockIdx.x] = tmp[255];
}

__global__ void scan2_kernel(unsigned int* __restrict__ bsum, int nb) {
    __shared__ unsigned int tmp[512];
    unsigned int v = (threadIdx.x < nb) ? bsum[threadIdx.x] : 0u;
    tmp[threadIdx.x] = v;
    __syncthreads();
    for (int ofs = 1; ofs < 512; ofs <<= 1) {
        unsigned int t = (threadIdx.x >= ofs) ? tmp[threadIdx.x - ofs] : 0u;
        __syncthreads();
        tmp[threadIdx.x] += t;
        __syncthreads();
    }
    if (threadIdx.x < nb) bsum[threadIdx.x] = tmp[threadIdx.x] - v;  // exclusive
}

__global__ void scan3_kernel(unsigned int* __restrict__ rowptr,
                             const unsigned int* __restrict__ bsum,
                             unsigned int* __restrict__ cursor) {
    int i = blockIdx.x * 256 + threadIdx.x;
    if (i < N_NODES) {
        unsigned int v = rowptr[i] + bsum[blockIdx.x];
        rowptr[i] = v;
        cursor[i] = v;
    }
}

// ---------------- CSR fill: only column indices (weights factored out) ----------------

__global__ void fill_kernel(const int* __restrict__ row, const int* __restrict__ col,
                            unsigned int* __restrict__ cursor,
                            int* __restrict__ ccol) {
    int e = blockIdx.x * blockDim.x + threadIdx.x;
    if (e >= E_EDGES) return;
    int r = row[e], c = col[e];
    if (r == c) return;
    unsigned int pos = atomicAdd(&cursor[r], 1u);
    ccol[pos] = c;
}

// ---------------- SpMM 64-dim: (Lv)[r] = -dis[r] * sum dis[c] v[c] ----------------

__global__ void spmm64_kernel(const unsigned int* __restrict__ rowptr,
                              const unsigned int* __restrict__ deg,
                              const unsigned int* __restrict__ ccol,
                              const float* __restrict__ dis,
                              const float* __restrict__ vin, float* __restrict__ vout) {
    int wid = blockIdx.x * 4 + (threadIdx.x >> 6);
    int lane = threadIdx.x & 63;
    if (wid >= N_NODES) return;
    unsigned int s = rowptr[wid];
    int pd = (int)((deg[wid] + 3u) & ~3u);
    float a0 = 0.0f, a1 = 0.0f, a2 = 0.0f, a3 = 0.0f;
    for (int e = 0; e < pd; e += 4) {
        unsigned int c0 = ccol[s + e + 0];
        unsigned int c1 = ccol[s + e + 1];
        unsigned int c2 = ccol[s + e + 2];
        unsigned int c3 = ccol[s + e + 3];
        // pads are 0xFFFFFFFF: weight index clamps to N (dis[N]=0), addr clamps to N-1
        float w0 = dis[min(c0, (unsigned int)N_NODES)];
        float w1 = dis[min(c1, (unsigned int)N_NODES)];
        float w2 = dis[min(c2, (unsigned int)N_NODES)];
        float w3 = dis[min(c3, (unsigned int)N_NODES)];
        float v0 = vin[(size_t)min(c0, (unsigned int)(N_NODES - 1)) * 64 + lane];
        float v1 = vin[(size_t)min(c1, (unsigned int)(N_NODES - 1)) * 64 + lane];
        float v2 = vin[(size_t)min(c2, (unsigned int)(N_NODES - 1)) * 64 + lane];
        float v3 = vin[(size_t)min(c3, (unsigned int)(N_NODES - 1)) * 64 + lane];
        a0 += w0 * v0;
        a1 += w1 * v1;
        a2 += w2 * v2;
        a3 += w3 * v3;
    }
    vout[(size_t)wid * 64 + lane] = -dis[wid] * ((a0 + a1) + (a2 + a3));
}

// ---------------- SpMM 16-dim with fused epilogues ----------------
// MODE 0: vout = add + 2*(Lv)   MODE 1: vout = add + (Lv)

template <int MODE>
__global__ void spmm16_kernel(const unsigned int* __restrict__ rowptr,
                              const unsigned int* __restrict__ deg,
                              const unsigned int* __restrict__ ccol,
                              const float* __restrict__ dis,
                              const float* __restrict__ vin, const float* __restrict__ add,
                              float* __restrict__ vout) {
    int wid = blockIdx.x * 16 + (threadIdx.x >> 4);
    int l16 = threadIdx.x & 15;
    if (wid >= N_NODES) return;
    unsigned int s = rowptr[wid];
    int pd = (int)((deg[wid] + 3u) & ~3u);
    float a0 = 0.0f, a1 = 0.0f, a2 = 0.0f, a3 = 0.0f;
    for (int e = 0; e < pd; e += 4) {
        unsigned int c0 = ccol[s + e + 0];
        unsigned int c1 = ccol[s + e + 1];
        unsigned int c2 = ccol[s + e + 2];
        unsigned int c3 = ccol[s + e + 3];
        float w0 = dis[min(c0, (unsigned int)N_NODES)];
        float w1 = dis[min(c1, (unsigned int)N_NODES)];
        float w2 = dis[min(c2, (unsigned int)N_NODES)];
        float w3 = dis[min(c3, (unsigned int)N_NODES)];
        a0 += w0 * vin[(size_t)min(c0, (unsigned int)(N_NODES - 1)) * 16 + l16];
        a1 += w1 * vin[(size_t)min(c1, (unsigned int)(N_NODES - 1)) * 16 + l16];
        a2 += w2 * vin[(size_t)min(c2, (unsigned int)(N_NODES - 1)) * 16 + l16];
        a3 += w3 * vin[(size_t)min(c3, (unsigned int)(N_NODES - 1)) * 16 + l16];
    }
    float acc = (a0 + a1) + (a2 + a3);
    float scl = (MODE == 0) ? (-2.0f * dis[wid]) : (-dis[wid]);
    vout[(size_t)wid * 16 + l16] = add[(size_t)wid * 16 + l16] + scl * acc;
}

// ---------------- layer-1 GEMM, register-blocked ----------------
// h[n][j] = relu( sum_k t0*W0' + t1*W1 + B*(2W2) + b1 ),  W0' = W0 - W2  (t2 folded)
// Block: 256 threads = 16 j-groups x 16 node-groups; thread = 8 nodes x 4 j.
// Weights (K=192 concat) staged once in LDS (48 KB); inputs read via 16-way
// broadcast global loads (L1-resident across k4 iterations).

#define GT_N 128

__global__ __launch_bounds__(256) void gemm1_kernel(
    const float* __restrict__ t0p, const float* __restrict__ t1p,
    const float* __restrict__ bp,
    const float* __restrict__ W1, const float* __restrict__ b1,
    float* __restrict__ h) {

    __shared__ float4 Ws[3 * 64 * 16];  // [192 k][16 jg] float4 = 48 KB

    const float4* Wg = (const float4*)W1;  // 3072 float4
    for (int f = threadIdx.x; f < 3072; f += 256) {
        float4 v;
        if (f < 1024) {
            float4 a = Wg[f], c = Wg[f + 2048];
            v = make_float4(a.x - c.x, a.y - c.y, a.z - c.z, a.w - c.w);
        } else if (f < 2048) {
            v = Wg[f];
        } else {
            float4 c = Wg[f];
            v = make_float4(2.0f * c.x, 2.0f * c.y, 2.0f * c.z, 2.0f * c.w);
        }
        Ws[f] = v;
    }
    __syncthreads();

    const int jg = threadIdx.x & 15;
    const int ng = threadIdx.x >> 4;
    const int base = blockIdx.x * GT_N;

    float4 acc[8];
#pragma unroll
    for (int i = 0; i < 8; i++) acc[i] = make_float4(0.f, 0.f, 0.f, 0.f);

    const float4* mat0 = (const float4*)t0p;
    const float4* mat1 = (const float4*)t1p;
    const float4* mat2 = (const float4*)bp;

#pragma unroll
    for (int m = 0; m < 3; m++) {
        const float4* T = (m == 0) ? mat0 : (m == 1) ? mat1 : mat2;
#pragma unroll 2
        for (int k4 = 0; k4 < 16; k4++) {
            float tv[8][4];
#pragma unroll
            for (int i = 0; i < 8; i++) {
                int n = base + ng + 16 * i;
                n = (n < N_NODES) ? n : (N_NODES - 1);
                float4 t = T[(size_t)n * 16 + k4];
                tv[i][0] = t.x; tv[i][1] = t.y; tv[i][2] = t.z; tv[i][3] = t.w;
            }
#pragma unroll
            for (int kk = 0; kk < 4; kk++) {
                float4 w = Ws[(m * 64 + k4 * 4 + kk) * 16 + jg];
#pragma unroll
                for (int i = 0; i < 8; i++) {
                    acc[i].x += tv[i][kk] * w.x;
                    acc[i].y += tv[i][kk] * w.y;
                    acc[i].z += tv[i][kk] * w.z;
                    acc[i].w += tv[i][kk] * w.w;
                }
            }
        }
    }

    float4 bb = ((const float4*)b1)[jg];
#pragma unroll
    for (int i = 0; i < 8; i++) {
        int n = base + ng + 16 * i;
        if (n < N_NODES) {
            float4 v;
            v.x = fmaxf(acc[i].x + bb.x, 0.0f);
            v.y = fmaxf(acc[i].y + bb.y, 0.0f);
            v.z = fmaxf(acc[i].z + bb.z, 0.0f);
            v.w = fmaxf(acc[i].w + bb.w, 0.0f);
            ((float4*)(h + (size_t)n * 64))[jg] = v;
        }
    }
}

// ---------------- layer-2 projection, register-blocked ----------------
// P = h@(W2_0 - W2_2) + b2, Q = h@W2_1, R = h@W2_2
// Block: 192 threads = 12 j-groups x 16 node-groups; thread = 8 nodes x 4 j.

__global__ __launch_bounds__(192) void proj_kernel(
    const float* __restrict__ h, const float* __restrict__ W2, const float* __restrict__ b2,
    float* __restrict__ P, float* __restrict__ Q, float* __restrict__ R) {

    __shared__ float4 Wp[64 * 12];  // [64 k][12 jg] float4 = 12 KB

    const float4* Wg = (const float4*)W2;  // 768 float4; mat m at m*256
    for (int f = threadIdx.x; f < 768; f += 192) {
        int i = f / 12, g = f % 12;
        float4 v;
        if (g < 4) {
            float4 a = Wg[i * 4 + g], c = Wg[512 + i * 4 + g];
            v = make_float4(a.x - c.x, a.y - c.y, a.z - c.z, a.w - c.w);
        } else if (g < 8) {
            v = Wg[256 + i * 4 + (g - 4)];
        } else {
            v = Wg[512 + i * 4 + (g - 8)];
        }
        Wp[f] = v;
    }
    __syncthreads();

    const int jg = threadIdx.x % 12;
    const int ng = threadIdx.x / 12;  // 0..15
    const int base = blockIdx.x * GT_N;

    float4 acc[8];
#pragma unroll
    for (int i = 0; i < 8; i++) acc[i] = make_float4(0.f, 0.f, 0.f, 0.f);

    const float4* H = (const float4*)h;
#pragma unroll 2
    for (int k4 = 0; k4 < 16; k4++) {
        float tv[8][4];
#pragma unroll
        for (int i = 0; i < 8; i++) {
            int n = base + ng + 16 * i;
            n = (n < N_NODES) ? n : (N_NODES - 1);
            float4 t = H[(size_t)n * 16 + k4];
            tv[i][0] = t.x; tv[i][1] = t.y; tv[i][2] = t.z; tv[i][3] = t.w;
        }
#pragma unroll
        for (int kk = 0; kk < 4; kk++) {
            float4 w = Wp[(k4 * 4 + kk) * 12 + jg];
#pragma unroll
            for (int i = 0; i < 8; i++) {
                acc[i].x += tv[i][kk] * w.x;
                acc[i].y += tv[i][kk] * w.y;
                acc[i].z += tv[i][kk] * w.z;
                acc[i].w += tv[i][kk] * w.w;
            }
        }
    }

    float4 badd = make_float4(0.f, 0.f, 0.f, 0.f);
    if (jg < 4) badd = ((const float4*)b2)[jg];
    float* dst = (jg < 4) ? P : (jg < 8) ? Q : R;
    int cg = (jg < 4) ? jg : (jg < 8) ? (jg - 4) : (jg - 8);
#pragma unroll
    for (int i = 0; i < 8; i++) {
        int n = base + ng + 16 * i;
        if (n < N_NODES) {
            float4 v;
            v.x = acc[i].x + badd.x;
            v.y = acc[i].y + badd.y;
            v.z = acc[i].z + badd.z;
            v.w = acc[i].w + badd.w;
            ((float4*)(dst + (size_t)n * 16))[cg] = v;
        }
    }
}

// ---------------- launch ----------------

extern "C" void kernel_launch(void* const* d_in, const int* in_sizes, int n_in,
                              void* d_out, int out_size, void* d_ws, size_t ws_size,
                              hipStream_t stream) {
    const float* x  = (const float*)d_in[0];
    const int* edge = (const int*)d_in[1];
    const float* W1 = (const float*)d_in[2];
    const float* b1 = (const float*)d_in[3];
    const float* W2 = (const float*)d_in[4];
    const float* b2 = (const float*)d_in[5];
    float* out = (float*)d_out;

    const int* row = edge;            // edge_index[0]
    const int* col = edge + E_EDGES;  // edge_index[1]

    // workspace layout
    char* ws = (char*)d_ws;
    size_t off = 0;
    auto alloc = [&](size_t bytes) {
        void* p = ws + off;
        off = (off + bytes + 255) & ~(size_t)255;
        return p;
    };
    unsigned int* deg    = (unsigned int*)alloc(N_NODES * 4);
    float*        dis    = (float*)alloc((N_NODES + 1) * 4);  // +1 sentinel (=0)
    unsigned int* rowptr = (unsigned int*)alloc(N_NODES * 4);
    unsigned int* cursor = (unsigned int*)alloc(N_NODES * 4);
    unsigned int* bsum   = (unsigned int*)alloc(512 * 4);
    unsigned int* ccol   = (unsigned int*)alloc((size_t)CSR_CAP * 4);
    float*        A      = (float*)alloc((size_t)N_NODES * 64 * 4);
    float*        B      = (float*)alloc((size_t)N_NODES * 64 * 4);
    float*        H      = (float*)alloc((size_t)N_NODES * 64 * 4);
    float*        P      = (float*)alloc((size_t)N_NODES * 16 * 4);
    float*        Q      = (float*)alloc((size_t)N_NODES * 16 * 4);
    float*        R      = (float*)alloc((size_t)N_NODES * 16 * 4);
    float*        S      = (float*)alloc((size_t)N_NODES * 16 * 4);

    const int nodeBlocks   = (N_NODES + 255) / 256;  // 391
    const int edgeBlocks   = (E_EDGES + 255) / 256;  // 6250
    const int spmm64Blocks = (N_NODES + 3) / 4;      // 1 wave/row
    const int spmm16Blocks = (N_NODES + 15) / 16;    // 16 lanes/row
    const int gemmBlocks   = (N_NODES + GT_N - 1) / GT_N;  // 782

    // ---- build norm + padded CSR ----
    hipMemsetAsync(deg, 0, N_NODES * 4, stream);
    hipMemsetAsync(ccol, 0xFF, (size_t)CSR_CAP * 4, stream);  // pad sentinel
    deg_kernel<<<edgeBlocks, 256, 0, stream>>>(row, col, deg);
    scan1_kernel<<<nodeBlocks, 256, 0, stream>>>(deg, rowptr, bsum, dis);
    scan2_kernel<<<1, 512, 0, stream>>>(bsum, nodeBlocks);
    scan3_kernel<<<nodeBlocks, 256, 0, stream>>>(rowptr, bsum, cursor);
    fill_kernel<<<edgeBlocks, 256, 0, stream>>>(row, col, cursor, (int*)ccol);

    // ---- layer 1 SpMMs: A = Lx, B = LA ----
    spmm64_kernel<<<spmm64Blocks, 256, 0, stream>>>(rowptr, deg, ccol, dis, x, A);
    spmm64_kernel<<<spmm64Blocks, 256, 0, stream>>>(rowptr, deg, ccol, dis, A, B);

    // ---- GEMMs: H = relu(layer1), then P,Q,R projections ----
    gemm1_kernel<<<gemmBlocks, 256, 0, stream>>>(x, A, B, W1, b1, H);
    proj_kernel<<<gemmBlocks, 192, 0, stream>>>(H, W2, b2, P, Q, R);

    // ---- layer 2 SpMMs: S = Q + 2*L(R); out = P + L(S) ----
    spmm16_kernel<0><<<spmm16Blocks, 256, 0, stream>>>(rowptr, deg, ccol, dis, R, Q, S);
    spmm16_kernel<1><<<spmm16Blocks, 256, 0, stream>>>(rowptr, deg, ccol, dis, S, P, out);
}

// Round 6
// 425.042 us; speedup vs baseline: 1.4277x; 1.1421x over previous
//
#include <hip/hip_runtime.h>

#define N_NODES 100000
#define E_EDGES 1600000
#define CSR_CAP (E_EDGES + 4 * N_NODES)  // padded capacity
#define FILL_G 8
#define ROWS_PER_G ((N_NODES + FILL_G - 1) / FILL_G)  // 12500

__device__ __forceinline__ float bf2f(unsigned short u) {
    return __uint_as_float(((unsigned int)u) << 16);
}
__device__ __forceinline__ unsigned short f2bf(float f) {
    unsigned int u = __float_as_uint(f);
    u += 0x7FFF + ((u >> 16) & 1u);  // round-to-nearest-even
    return (unsigned short)(u >> 16);
}

// ---------------- degree ----------------

__global__ void deg_kernel(const int* __restrict__ row, const int* __restrict__ col,
                           unsigned int* __restrict__ deg) {
    int e = blockIdx.x * blockDim.x + threadIdx.x;
    if (e >= E_EDGES) return;
    int r = row[e], c = col[e];
    if (r != c) atomicAdd(&deg[r], 1u);
}

// ---------------- scan of PADDED deg -> rowptr ; dis fused ----------------

__global__ void scan1_kernel(const unsigned int* __restrict__ deg,
                             unsigned int* __restrict__ rowptr,
                             unsigned int* __restrict__ bsum,
                             float* __restrict__ dis) {
    __shared__ unsigned int tmp[256];
    int i = blockIdx.x * 256 + threadIdx.x;
    unsigned int d = (i < N_NODES) ? deg[i] : 0u;
    if (i < N_NODES) dis[i] = (d > 0u) ? rsqrtf((float)d) : 0.0f;
    if (i == N_NODES) dis[i] = 0.0f;  // sentinel: zero weight for pads
    unsigned int v = (d + 3u) & ~3u;  // pad each row to multiple of 4
    tmp[threadIdx.x] = v;
    __syncthreads();
    for (int ofs = 1; ofs < 256; ofs <<= 1) {
        unsigned int t = (threadIdx.x >= ofs) ? tmp[threadIdx.x - ofs] : 0u;
        __syncthreads();
        tmp[threadIdx.x] += t;
        __syncthreads();
    }
    if (i < N_NODES) rowptr[i] = tmp[threadIdx.x] - v;  // local exclusive (padded)
    if (threadIdx.x == 255) bsum[blockIdx.x] = tmp[255];
}

__global__ void scan2_kernel(unsigned int* __restrict__ bsum, int nb) {
    __shared__ unsigned int tmp[512];
    unsigned int v = (threadIdx.x < nb) ? bsum[threadIdx.x] : 0u;
    tmp[threadIdx.x] = v;
    __syncthreads();
    for (int ofs = 1; ofs < 512; ofs <<= 1) {
        unsigned int t = (threadIdx.x >= ofs) ? tmp[threadIdx.x - ofs] : 0u;
        __syncthreads();
        tmp[threadIdx.x] += t;
        __syncthreads();
    }
    if (threadIdx.x < nb) bsum[threadIdx.x] = tmp[threadIdx.x] - v;  // exclusive
}

__global__ void scan3_kernel(unsigned int* __restrict__ rowptr,
                             const unsigned int* __restrict__ bsum,
                             unsigned int* __restrict__ cursor) {
    int i = blockIdx.x * 256 + threadIdx.x;
    if (i < N_NODES) {
        unsigned int v = rowptr[i] + bsum[blockIdx.x];
        rowptr[i] = v;
        cursor[i] = v;
    }
}

// ---------------- XCD-partitioned CSR fill ----------------
// Group g = blockIdx&7 (round-robin -> same XCD heuristic) owns rows
// [g*12500,(g+1)*12500); each group streams ALL edges but writes only its own
// ~1MB ccol slice -> slice stays in one XCD L2, write-back ~8MB not ~100MB.
// Correct for ANY block->XCD mapping (only locality depends on it).

__global__ void fill_kernel(const int* __restrict__ row, const int* __restrict__ col,
                            unsigned int* __restrict__ cursor,
                            int* __restrict__ ccol) {
    int g = blockIdx.x & (FILL_G - 1);
    int chunk = blockIdx.x >> 3;
    int nch = gridDim.x >> 3;
    int lo = g * ROWS_PER_G;
    int stride = nch * blockDim.x;
    for (int e = chunk * blockDim.x + threadIdx.x; e < E_EDGES; e += stride) {
        int r = row[e];
        if ((unsigned int)(r - lo) < (unsigned int)ROWS_PER_G) {
            int c = col[e];
            if (r != c) {
                unsigned int pos = atomicAdd(&cursor[r], 1u);
                ccol[pos] = c;
            }
        }
    }
}

// ---------------- f32 -> bf16 conversion (x copy) ----------------

__global__ void conv_kernel(const float* __restrict__ x, unsigned short* __restrict__ xb) {
    int i = blockIdx.x * 256 + threadIdx.x;  // over N*64/4 quads
    if (i >= N_NODES * 16) return;
    float4 v = ((const float4*)x)[i];
    ushort4 o;
    o.x = f2bf(v.x); o.y = f2bf(v.y); o.z = f2bf(v.z); o.w = f2bf(v.w);
    ((ushort4*)xb)[i] = o;
}

// ---------------- SpMM 64-dim bf16: (Lv)[r] = -dis[r] * sum dis[c] v[c] ----------------

__global__ void spmm64_kernel(const unsigned int* __restrict__ rowptr,
                              const unsigned int* __restrict__ deg,
                              const unsigned int* __restrict__ ccol,
                              const float* __restrict__ dis,
                              const unsigned short* __restrict__ vin,
                              unsigned short* __restrict__ vout) {
    int wid = blockIdx.x * 4 + (threadIdx.x >> 6);
    int lane = threadIdx.x & 63;
    if (wid >= N_NODES) return;
    unsigned int s = rowptr[wid];
    int pd = (int)((deg[wid] + 3u) & ~3u);
    float a0 = 0.0f, a1 = 0.0f, a2 = 0.0f, a3 = 0.0f;
    for (int e = 0; e < pd; e += 4) {
        unsigned int c0 = ccol[s + e + 0];
        unsigned int c1 = ccol[s + e + 1];
        unsigned int c2 = ccol[s + e + 2];
        unsigned int c3 = ccol[s + e + 3];
        // pads are 0xFFFFFFFF: weight index clamps to N (dis[N]=0), addr clamps to N-1
        float w0 = dis[min(c0, (unsigned int)N_NODES)];
        float w1 = dis[min(c1, (unsigned int)N_NODES)];
        float w2 = dis[min(c2, (unsigned int)N_NODES)];
        float w3 = dis[min(c3, (unsigned int)N_NODES)];
        float v0 = bf2f(vin[(size_t)min(c0, (unsigned int)(N_NODES - 1)) * 64 + lane]);
        float v1 = bf2f(vin[(size_t)min(c1, (unsigned int)(N_NODES - 1)) * 64 + lane]);
        float v2 = bf2f(vin[(size_t)min(c2, (unsigned int)(N_NODES - 1)) * 64 + lane]);
        float v3 = bf2f(vin[(size_t)min(c3, (unsigned int)(N_NODES - 1)) * 64 + lane]);
        a0 += w0 * v0;
        a1 += w1 * v1;
        a2 += w2 * v2;
        a3 += w3 * v3;
    }
    vout[(size_t)wid * 64 + lane] = f2bf(-dis[wid] * ((a0 + a1) + (a2 + a3)));
}

// ---------------- SpMM 16-dim bf16 gather with fused epilogues ----------------
// MODE 0: S(bf16) = Q(f32) + 2*(Lv)   MODE 1: out(f32) = P(f32) + (Lv)

template <int MODE>
__global__ void spmm16_kernel(const unsigned int* __restrict__ rowptr,
                              const unsigned int* __restrict__ deg,
                              const unsigned int* __restrict__ ccol,
                              const float* __restrict__ dis,
                              const unsigned short* __restrict__ vin,
                              const float* __restrict__ add,
                              unsigned short* __restrict__ voutb,
                              float* __restrict__ voutf) {
    int wid = blockIdx.x * 16 + (threadIdx.x >> 4);
    int l16 = threadIdx.x & 15;
    if (wid >= N_NODES) return;
    unsigned int s = rowptr[wid];
    int pd = (int)((deg[wid] + 3u) & ~3u);
    float a0 = 0.0f, a1 = 0.0f, a2 = 0.0f, a3 = 0.0f;
    for (int e = 0; e < pd; e += 4) {
        unsigned int c0 = ccol[s + e + 0];
        unsigned int c1 = ccol[s + e + 1];
        unsigned int c2 = ccol[s + e + 2];
        unsigned int c3 = ccol[s + e + 3];
        float w0 = dis[min(c0, (unsigned int)N_NODES)];
        float w1 = dis[min(c1, (unsigned int)N_NODES)];
        float w2 = dis[min(c2, (unsigned int)N_NODES)];
        float w3 = dis[min(c3, (unsigned int)N_NODES)];
        a0 += w0 * bf2f(vin[(size_t)min(c0, (unsigned int)(N_NODES - 1)) * 16 + l16]);
        a1 += w1 * bf2f(vin[(size_t)min(c1, (unsigned int)(N_NODES - 1)) * 16 + l16]);
        a2 += w2 * bf2f(vin[(size_t)min(c2, (unsigned int)(N_NODES - 1)) * 16 + l16]);
        a3 += w3 * bf2f(vin[(size_t)min(c3, (unsigned int)(N_NODES - 1)) * 16 + l16]);
    }
    float acc = (a0 + a1) + (a2 + a3);
    float scl = (MODE == 0) ? (-2.0f * dis[wid]) : (-dis[wid]);
    float r = add[(size_t)wid * 16 + l16] + scl * acc;
    if (MODE == 0) voutb[(size_t)wid * 16 + l16] = f2bf(r);
    else           voutf[(size_t)wid * 16 + l16] = r;
}

// ---------------- layer-1 GEMM, register-blocked, mixed f32/bf16 inputs ----------------
// h = relu(x@(W0-W2) + A@W1 + B@(2*W2) + b1); x f32, A/B bf16, h f32.
// Block: 256 threads = 16 jg x 16 ng; thread = 8 nodes x 4 j.

#define GT_N 128

__global__ __launch_bounds__(256) void gemm1_kernel(
    const float* __restrict__ x, const unsigned short* __restrict__ Ab,
    const unsigned short* __restrict__ Bb,
    const float* __restrict__ W1, const float* __restrict__ b1,
    float* __restrict__ h) {

    __shared__ float4 Ws[3 * 64 * 16];  // [192 k][16 jg] float4 = 48 KB

    const float4* Wg = (const float4*)W1;  // 3072 float4
    for (int f = threadIdx.x; f < 3072; f += 256) {
        float4 v;
        if (f < 1024) {
            float4 a = Wg[f], c = Wg[f + 2048];
            v = make_float4(a.x - c.x, a.y - c.y, a.z - c.z, a.w - c.w);
        } else if (f < 2048) {
            v = Wg[f];
        } else {
            float4 c = Wg[f];
            v = make_float4(2.0f * c.x, 2.0f * c.y, 2.0f * c.z, 2.0f * c.w);
        }
        Ws[f] = v;
    }
    __syncthreads();

    const int jg = threadIdx.x & 15;
    const int ng = threadIdx.x >> 4;
    const int base = blockIdx.x * GT_N;

    float4 acc[8];
#pragma unroll
    for (int i = 0; i < 8; i++) acc[i] = make_float4(0.f, 0.f, 0.f, 0.f);

    // m = 0: x (f32)
    {
        const float4* T = (const float4*)x;
#pragma unroll 2
        for (int k4 = 0; k4 < 16; k4++) {
            float tv[8][4];
#pragma unroll
            for (int i = 0; i < 8; i++) {
                int n = base + ng + 16 * i;
                n = (n < N_NODES) ? n : (N_NODES - 1);
                float4 t = T[(size_t)n * 16 + k4];
                tv[i][0] = t.x; tv[i][1] = t.y; tv[i][2] = t.z; tv[i][3] = t.w;
            }
#pragma unroll
            for (int kk = 0; kk < 4; kk++) {
                float4 w = Ws[(k4 * 4 + kk) * 16 + jg];
#pragma unroll
                for (int i = 0; i < 8; i++) {
                    acc[i].x += tv[i][kk] * w.x;
                    acc[i].y += tv[i][kk] * w.y;
                    acc[i].z += tv[i][kk] * w.z;
                    acc[i].w += tv[i][kk] * w.w;
                }
            }
        }
    }
    // m = 1,2: A, B (bf16)
    const unsigned short* mats[2] = {Ab, Bb};
#pragma unroll
    for (int m = 0; m < 2; m++) {
        const ushort4* T = (const ushort4*)mats[m];
#pragma unroll 2
        for (int k4 = 0; k4 < 16; k4++) {
            float tv[8][4];
#pragma unroll
            for (int i = 0; i < 8; i++) {
                int n = base + ng + 16 * i;
                n = (n < N_NODES) ? n : (N_NODES - 1);
                ushort4 t = T[(size_t)n * 16 + k4];
                tv[i][0] = bf2f(t.x); tv[i][1] = bf2f(t.y);
                tv[i][2] = bf2f(t.z); tv[i][3] = bf2f(t.w);
            }
#pragma unroll
            for (int kk = 0; kk < 4; kk++) {
                float4 w = Ws[((m + 1) * 64 + k4 * 4 + kk) * 16 + jg];
#pragma unroll
                for (int i = 0; i < 8; i++) {
                    acc[i].x += tv[i][kk] * w.x;
                    acc[i].y += tv[i][kk] * w.y;
                    acc[i].z += tv[i][kk] * w.z;
                    acc[i].w += tv[i][kk] * w.w;
                }
            }
        }
    }

    float4 bb = ((const float4*)b1)[jg];
#pragma unroll
    for (int i = 0; i < 8; i++) {
        int n = base + ng + 16 * i;
        if (n < N_NODES) {
            float4 v;
            v.x = fmaxf(acc[i].x + bb.x, 0.0f);
            v.y = fmaxf(acc[i].y + bb.y, 0.0f);
            v.z = fmaxf(acc[i].z + bb.z, 0.0f);
            v.w = fmaxf(acc[i].w + bb.w, 0.0f);
            ((float4*)(h + (size_t)n * 64))[jg] = v;
        }
    }
}

// ---------------- layer-2 projection: P,Q f32; R bf16 ----------------
// P = h@(W2_0 - W2_2) + b2, Q = h@W2_1, R = h@W2_2

__global__ __launch_bounds__(192) void proj_kernel(
    const float* __restrict__ h, const float* __restrict__ W2, const float* __restrict__ b2,
    float* __restrict__ P, float* __restrict__ Q, unsigned short* __restrict__ Rb) {

    __shared__ float4 Wp[64 * 12];  // [64 k][12 jg] float4 = 12 KB

    const float4* Wg = (const float4*)W2;  // 768 float4; mat m at m*256
    for (int f = threadIdx.x; f < 768; f += 192) {
        int i = f / 12, g = f % 12;
        float4 v;
        if (g < 4) {
            float4 a = Wg[i * 4 + g], c = Wg[512 + i * 4 + g];
            v = make_float4(a.x - c.x, a.y - c.y, a.z - c.z, a.w - c.w);
        } else if (g < 8) {
            v = Wg[256 + i * 4 + (g - 4)];
        } else {
            v = Wg[512 + i * 4 + (g - 8)];
        }
        Wp[f] = v;
    }
    __syncthreads();

    const int jg = threadIdx.x % 12;
    const int ng = threadIdx.x / 12;  // 0..15
    const int base = blockIdx.x * GT_N;

    float4 acc[8];
#pragma unroll
    for (int i = 0; i < 8; i++) acc[i] = make_float4(0.f, 0.f, 0.f, 0.f);

    const float4* H = (const float4*)h;
#pragma unroll 2
    for (int k4 = 0; k4 < 16; k4++) {
        float tv[8][4];
#pragma unroll
        for (int i = 0; i < 8; i++) {
            int n = base + ng + 16 * i;
            n = (n < N_NODES) ? n : (N_NODES - 1);
            float4 t = H[(size_t)n * 16 + k4];
            tv[i][0] = t.x; tv[i][1] = t.y; tv[i][2] = t.z; tv[i][3] = t.w;
        }
#pragma unroll
        for (int kk = 0; kk < 4; kk++) {
            float4 w = Wp[(k4 * 4 + kk) * 12 + jg];
#pragma unroll
            for (int i = 0; i < 8; i++) {
                acc[i].x += tv[i][kk] * w.x;
                acc[i].y += tv[i][kk] * w.y;
                acc[i].z += tv[i][kk] * w.z;
                acc[i].w += tv[i][kk] * w.w;
            }
        }
    }

#pragma unroll
    for (int i = 0; i < 8; i++) {
        int n = base + ng + 16 * i;
        if (n >= N_NODES) continue;
        if (jg < 4) {
            float4 bv = ((const float4*)b2)[jg];
            float4 v = make_float4(acc[i].x + bv.x, acc[i].y + bv.y,
                                   acc[i].z + bv.z, acc[i].w + bv.w);
            ((float4*)(P + (size_t)n * 16))[jg] = v;
        } else if (jg < 8) {
            ((float4*)(Q + (size_t)n * 16))[jg - 4] =
                make_float4(acc[i].x, acc[i].y, acc[i].z, acc[i].w);
        } else {
            ushort4 v;
            v.x = f2bf(acc[i].x); v.y = f2bf(acc[i].y);
            v.z = f2bf(acc[i].z); v.w = f2bf(acc[i].w);
            *(ushort4*)(Rb + (size_t)n * 16 + (jg - 8) * 4) = v;
        }
    }
}

// ---------------- launch ----------------

extern "C" void kernel_launch(void* const* d_in, const int* in_sizes, int n_in,
                              void* d_out, int out_size, void* d_ws, size_t ws_size,
                              hipStream_t stream) {
    const float* x  = (const float*)d_in[0];
    const int* edge = (const int*)d_in[1];
    const float* W1 = (const float*)d_in[2];
    const float* b1 = (const float*)d_in[3];
    const float* W2 = (const float*)d_in[4];
    const float* b2 = (const float*)d_in[5];
    float* out = (float*)d_out;

    const int* row = edge;            // edge_index[0]
    const int* col = edge + E_EDGES;  // edge_index[1]

    // workspace layout
    char* ws = (char*)d_ws;
    size_t off = 0;
    auto alloc = [&](size_t bytes) {
        void* p = ws + off;
        off = (off + bytes + 255) & ~(size_t)255;
        return p;
    };
    unsigned int*   deg    = (unsigned int*)alloc(N_NODES * 4);
    float*          dis    = (float*)alloc((N_NODES + 1) * 4);  // +1 sentinel (=0)
    unsigned int*   rowptr = (unsigned int*)alloc(N_NODES * 4);
    unsigned int*   cursor = (unsigned int*)alloc(N_NODES * 4);
    unsigned int*   bsum   = (unsigned int*)alloc(512 * 4);
    unsigned int*   ccol   = (unsigned int*)alloc((size_t)CSR_CAP * 4);
    unsigned short* xbf    = (unsigned short*)alloc((size_t)N_NODES * 64 * 2);
    unsigned short* A      = (unsigned short*)alloc((size_t)N_NODES * 64 * 2);
    unsigned short* B      = (unsigned short*)alloc((size_t)N_NODES * 64 * 2);
    float*          H      = (float*)alloc((size_t)N_NODES * 64 * 4);
    float*          P      = (float*)alloc((size_t)N_NODES * 16 * 4);
    float*          Q      = (float*)alloc((size_t)N_NODES * 16 * 4);
    unsigned short* R      = (unsigned short*)alloc((size_t)N_NODES * 16 * 2);
    unsigned short* S      = (unsigned short*)alloc((size_t)N_NODES * 16 * 2);

    const int nodeBlocks   = (N_NODES + 255) / 256;  // 391
    const int edgeBlocks   = (E_EDGES + 255) / 256;  // 6250
    const int spmm64Blocks = (N_NODES + 3) / 4;      // 1 wave/row
    const int spmm16Blocks = (N_NODES + 15) / 16;    // 16 lanes/row
    const int gemmBlocks   = (N_NODES + GT_N - 1) / GT_N;  // 782
    const int fillBlocks   = 256 * FILL_G;           // 256 chunks x 8 groups

    // ---- build norm + padded CSR ----
    hipMemsetAsync(deg, 0, N_NODES * 4, stream);
    hipMemsetAsync(ccol, 0xFF, (size_t)CSR_CAP * 4, stream);  // pad sentinel
    deg_kernel<<<edgeBlocks, 256, 0, stream>>>(row, col, deg);
    scan1_kernel<<<nodeBlocks, 256, 0, stream>>>(deg, rowptr, bsum, dis);
    scan2_kernel<<<1, 512, 0, stream>>>(bsum, nodeBlocks);
    scan3_kernel<<<nodeBlocks, 256, 0, stream>>>(rowptr, bsum, cursor);
    fill_kernel<<<fillBlocks, 256, 0, stream>>>(row, col, cursor, (int*)ccol);
    conv_kernel<<<(N_NODES * 16 + 255) / 256, 256, 0, stream>>>(x, xbf);

    // ---- layer 1 SpMMs: A = Lx, B = LA (bf16 storage, f32 accumulate) ----
    spmm64_kernel<<<spmm64Blocks, 256, 0, stream>>>(rowptr, deg, ccol, dis, xbf, A);
    spmm64_kernel<<<spmm64Blocks, 256, 0, stream>>>(rowptr, deg, ccol, dis, A, B);

    // ---- GEMMs: H = relu(layer1), then P,Q (f32), R (bf16) projections ----
    gemm1_kernel<<<gemmBlocks, 256, 0, stream>>>(x, A, B, W1, b1, H);
    proj_kernel<<<gemmBlocks, 192, 0, stream>>>(H, W2, b2, P, Q, R);

    // ---- layer 2 SpMMs: S = Q + 2*L(R); out = P + L(S) ----
    spmm16_kernel<0><<<spmm16Blocks, 256, 0, stream>>>(rowptr, deg, ccol, dis, R, Q, S, nullptr);
    spmm16_kernel<1><<<spmm16Blocks, 256, 0, stream>>>(rowptr, deg, ccol, dis, S, P, nullptr, out);
}

// Round 7
// 408.274 us; speedup vs baseline: 1.4864x; 1.0411x over previous
//
#include <hip/hip_runtime.h>

#define N_NODES 100000
#define E_EDGES 1600000
#define CSR_CAP (E_EDGES + 4 * N_NODES)  // padded capacity
#define FILL_G 8
#define ROWS_PER_G ((N_NODES + FILL_G - 1) / FILL_G)  // 12500

__device__ __forceinline__ float bf2f(unsigned short u) {
    return __uint_as_float(((unsigned int)u) << 16);
}
__device__ __forceinline__ unsigned short f2bf(float f) {
    unsigned int u = __float_as_uint(f);
    u += 0x7FFF + ((u >> 16) & 1u);  // round-to-nearest-even
    return (unsigned short)(u >> 16);
}
__device__ __forceinline__ unsigned int pack2bf(float a, float b) {
    return (unsigned int)f2bf(a) | ((unsigned int)f2bf(b) << 16);
}

// ---------------- degree ----------------

__global__ void deg_kernel(const int* __restrict__ row, const int* __restrict__ col,
                           unsigned int* __restrict__ deg) {
    int e = blockIdx.x * blockDim.x + threadIdx.x;
    if (e >= E_EDGES) return;
    int r = row[e], c = col[e];
    if (r != c) atomicAdd(&deg[r], 1u);
}

// ---------------- scan of PADDED deg -> rowptr ; dis fused ----------------

__global__ void scan1_kernel(const unsigned int* __restrict__ deg,
                             unsigned int* __restrict__ rowptr,
                             unsigned int* __restrict__ bsum,
                             float* __restrict__ dis) {
    __shared__ unsigned int tmp[256];
    int i = blockIdx.x * 256 + threadIdx.x;
    unsigned int d = (i < N_NODES) ? deg[i] : 0u;
    if (i < N_NODES) dis[i] = (d > 0u) ? rsqrtf((float)d) : 0.0f;
    unsigned int v = (d + 3u) & ~3u;  // pad each row to multiple of 4
    tmp[threadIdx.x] = v;
    __syncthreads();
    for (int ofs = 1; ofs < 256; ofs <<= 1) {
        unsigned int t = (threadIdx.x >= ofs) ? tmp[threadIdx.x - ofs] : 0u;
        __syncthreads();
        tmp[threadIdx.x] += t;
        __syncthreads();
    }
    if (i < N_NODES) rowptr[i] = tmp[threadIdx.x] - v;  // local exclusive (padded)
    if (threadIdx.x == 255) bsum[blockIdx.x] = tmp[255];
}

__global__ void scan2_kernel(unsigned int* __restrict__ bsum, int nb) {
    __shared__ unsigned int tmp[512];
    unsigned int v = (threadIdx.x < nb) ? bsum[threadIdx.x] : 0u;
    tmp[threadIdx.x] = v;
    __syncthreads();
    for (int ofs = 1; ofs < 512; ofs <<= 1) {
        unsigned int t = (threadIdx.x >= ofs) ? tmp[threadIdx.x - ofs] : 0u;
        __syncthreads();
        tmp[threadIdx.x] += t;
        __syncthreads();
    }
    if (threadIdx.x < nb) bsum[threadIdx.x] = tmp[threadIdx.x] - v;  // exclusive
}

__global__ void scan3_kernel(unsigned int* __restrict__ rowptr,
                             const unsigned int* __restrict__ bsum,
                             unsigned int* __restrict__ cursor) {
    int i = blockIdx.x * 256 + threadIdx.x;
    if (i < N_NODES) {
        unsigned int v = rowptr[i] + bsum[blockIdx.x];
        rowptr[i] = v;
        cursor[i] = v;
    }
}

// ---------------- XCD-partitioned CSR fill ----------------

__global__ void fill_kernel(const int* __restrict__ row, const int* __restrict__ col,
                            unsigned int* __restrict__ cursor,
                            int* __restrict__ ccol) {
    int g = blockIdx.x & (FILL_G - 1);
    int chunk = blockIdx.x >> 3;
    int nch = gridDim.x >> 3;
    int lo = g * ROWS_PER_G;
    int stride = nch * blockDim.x;
    for (int e = chunk * blockDim.x + threadIdx.x; e < E_EDGES; e += stride) {
        int r = row[e];
        if ((unsigned int)(r - lo) < (unsigned int)ROWS_PER_G) {
            int c = col[e];
            if (r != c) {
                unsigned int pos = atomicAdd(&cursor[r], 1u);
                ccol[pos] = c;
            }
        }
    }
}

// ---------------- xs = bf16(dis * x), with zero sentinel row N ----------------

__global__ void conv_kernel(const float* __restrict__ x, const float* __restrict__ dis,
                            unsigned short* __restrict__ xs) {
    int i = blockIdx.x * 256 + threadIdx.x;  // quad index over (N+1)*16
    if (i >= (N_NODES + 1) * 16) return;
    int n = i >> 4;
    if (n >= N_NODES) {
        ((ushort4*)xs)[i] = make_ushort4(0, 0, 0, 0);
        return;
    }
    float d = dis[n];
    float4 v = ((const float4*)x)[i];
    ushort4 o;
    o.x = f2bf(v.x * d); o.y = f2bf(v.y * d); o.z = f2bf(v.z * d); o.w = f2bf(v.w * d);
    ((ushort4*)xs)[i] = o;
}

// ---------------- SpMM 64-dim: pure neighbor-sum of pre-scaled rows ----------------
// Input rows are dis-scaled; acc = sum vin[c]. TWO: write vout_s = -d^2*acc (scaled
// for next SpMM) and vout_u = -d*acc (unscaled for GEMM). !TWO: vout_u = -d*acc only.
// Packing: lane = (half, sub); gather loads bf16x2 pair `sub` of 2 rows per instr.
// 3 VMEM per 4 edges (uint4 ccol + 2 packed gathers).

template <bool TWO>
__global__ void spmm64_kernel(const unsigned int* __restrict__ rowptr,
                              const unsigned int* __restrict__ deg,
                              const unsigned int* __restrict__ ccol,
                              const float* __restrict__ dis,
                              const unsigned short* __restrict__ vin,
                              unsigned short* __restrict__ vout_s,
                              unsigned short* __restrict__ vout_u) {
    int wid = blockIdx.x * 4 + (threadIdx.x >> 6);
    int lane = threadIdx.x & 63;
    int half = lane >> 5, sub = lane & 31;
    if (wid > N_NODES) return;
    if (wid == N_NODES) {  // zero sentinel rows
        if (half == 0) {
            if (TWO) ((unsigned int*)(vout_s + ((size_t)N_NODES << 6)))[sub] = 0u;
            ((unsigned int*)(vout_u + ((size_t)N_NODES << 6)))[sub] = 0u;
        }
        return;
    }
    unsigned int s = rowptr[wid];
    int pd = (int)((deg[wid] + 3u) & ~3u);
    float ax = 0.f, ay = 0.f, bx = 0.f, by = 0.f;
    for (int e = 0; e < pd; e += 4) {
        uint4 cc = *(const uint4*)(ccol + s + e);
        unsigned int cA = half ? cc.y : cc.x;  // edges e+0 / e+1
        unsigned int cB = half ? cc.w : cc.z;  // edges e+2 / e+3
        cA = min(cA, (unsigned int)N_NODES);   // pads (0xFF..) -> zero row N
        cB = min(cB, (unsigned int)N_NODES);
        unsigned int pA = *(const unsigned int*)(vin + ((size_t)cA << 6) + (sub << 1));
        unsigned int pB = *(const unsigned int*)(vin + ((size_t)cB << 6) + (sub << 1));
        ax += bf2f((unsigned short)pA); ay += bf2f((unsigned short)(pA >> 16));
        bx += bf2f((unsigned short)pB); by += bf2f((unsigned short)(pB >> 16));
    }
    float vx = ax + bx, vy = ay + by;
    vx += __shfl_xor(vx, 32);
    vy += __shfl_xor(vy, 32);
    if (half == 0) {
        float d = dis[wid];
        if (TWO) {
            float s2 = -d * d;
            ((unsigned int*)(vout_s + ((size_t)wid << 6)))[sub] = pack2bf(s2 * vx, s2 * vy);
        }
        ((unsigned int*)(vout_u + ((size_t)wid << 6)))[sub] = pack2bf(-d * vx, -d * vy);
    }
}

// ---------------- SpMM 16-dim, same packing (8-lane halves within 16-lane group) ----
// MODE 0: Ss = d*(Q - 2*d*acc)  (bf16, + sentinel row N)
// MODE 1: out = P - d*acc       (f32, final output)

template <int MODE>
__global__ void spmm16_kernel(const unsigned int* __restrict__ rowptr,
                              const unsigned int* __restrict__ deg,
                              const unsigned int* __restrict__ ccol,
                              const float* __restrict__ dis,
                              const unsigned short* __restrict__ vin,
                              const float* __restrict__ add,
                              unsigned short* __restrict__ voutb,
                              float* __restrict__ voutf) {
    int wid = blockIdx.x * 16 + (threadIdx.x >> 4);
    int s16 = threadIdx.x & 15;
    int half = s16 >> 3, sub = s16 & 7;
    if (MODE == 0) {
        if (wid > N_NODES) return;
        if (wid == N_NODES) {
            if (half == 0) ((unsigned int*)(voutb + ((size_t)N_NODES << 4)))[sub] = 0u;
            return;
        }
    } else {
        if (wid >= N_NODES) return;
    }
    unsigned int s = rowptr[wid];
    int pd = (int)((deg[wid] + 3u) & ~3u);
    float ax = 0.f, ay = 0.f, bx = 0.f, by = 0.f;
    for (int e = 0; e < pd; e += 4) {
        uint4 cc = *(const uint4*)(ccol + s + e);
        unsigned int cA = half ? cc.y : cc.x;
        unsigned int cB = half ? cc.w : cc.z;
        cA = min(cA, (unsigned int)N_NODES);
        cB = min(cB, (unsigned int)N_NODES);
        unsigned int pA = *(const unsigned int*)(vin + ((size_t)cA << 4) + (sub << 1));
        unsigned int pB = *(const unsigned int*)(vin + ((size_t)cB << 4) + (sub << 1));
        ax += bf2f((unsigned short)pA); ay += bf2f((unsigned short)(pA >> 16));
        bx += bf2f((unsigned short)pB); by += bf2f((unsigned short)(pB >> 16));
    }
    float vx = ax + bx, vy = ay + by;
    vx += __shfl_xor(vx, 8);
    vy += __shfl_xor(vy, 8);
    if (half == 0) {
        float d = dis[wid];
        float2 q = *(const float2*)(add + ((size_t)wid << 4) + (sub << 1));
        if (MODE == 0) {
            float rx = d * (q.x - 2.f * d * vx);
            float ry = d * (q.y - 2.f * d * vy);
            ((unsigned int*)(voutb + ((size_t)wid << 4)))[sub] = pack2bf(rx, ry);
        } else {
            float2 o;
            o.x = q.x - d * vx;
            o.y = q.y - d * vy;
            *(float2*)(voutf + ((size_t)wid << 4) + (sub << 1)) = o;
        }
    }
}

// ---------------- layer-1 GEMM, register-blocked, mixed f32/bf16 inputs ----------------
// h = relu(x@(W0-W2) + A@W1 + B@(2*W2) + b1); x f32, A/B bf16 (unscaled), h f32.

#define GT_N 128

__global__ __launch_bounds__(256) void gemm1_kernel(
    const float* __restrict__ x, const unsigned short* __restrict__ Ab,
    const unsigned short* __restrict__ Bb,
    const float* __restrict__ W1, const float* __restrict__ b1,
    float* __restrict__ h) {

    __shared__ float4 Ws[3 * 64 * 16];  // [192 k][16 jg] float4 = 48 KB

    const float4* Wg = (const float4*)W1;  // 3072 float4
    for (int f = threadIdx.x; f < 3072; f += 256) {
        float4 v;
        if (f < 1024) {
            float4 a = Wg[f], c = Wg[f + 2048];
            v = make_float4(a.x - c.x, a.y - c.y, a.z - c.z, a.w - c.w);
        } else if (f < 2048) {
            v = Wg[f];
        } else {
            float4 c = Wg[f];
            v = make_float4(2.0f * c.x, 2.0f * c.y, 2.0f * c.z, 2.0f * c.w);
        }
        Ws[f] = v;
    }
    __syncthreads();

    const int jg = threadIdx.x & 15;
    const int ng = threadIdx.x >> 4;
    const int base = blockIdx.x * GT_N;

    float4 acc[8];
#pragma unroll
    for (int i = 0; i < 8; i++) acc[i] = make_float4(0.f, 0.f, 0.f, 0.f);

    // m = 0: x (f32)
    {
        const float4* T = (const float4*)x;
#pragma unroll 2
        for (int k4 = 0; k4 < 16; k4++) {
            float tv[8][4];
#pragma unroll
            for (int i = 0; i < 8; i++) {
                int n = base + ng + 16 * i;
                n = (n < N_NODES) ? n : (N_NODES - 1);
                float4 t = T[(size_t)n * 16 + k4];
                tv[i][0] = t.x; tv[i][1] = t.y; tv[i][2] = t.z; tv[i][3] = t.w;
            }
#pragma unroll
            for (int kk = 0; kk < 4; kk++) {
                float4 w = Ws[(k4 * 4 + kk) * 16 + jg];
#pragma unroll
                for (int i = 0; i < 8; i++) {
                    acc[i].x += tv[i][kk] * w.x;
                    acc[i].y += tv[i][kk] * w.y;
                    acc[i].z += tv[i][kk] * w.z;
                    acc[i].w += tv[i][kk] * w.w;
                }
            }
        }
    }
    // m = 1,2: A, B (bf16)
    const unsigned short* mats[2] = {Ab, Bb};
#pragma unroll
    for (int m = 0; m < 2; m++) {
        const ushort4* T = (const ushort4*)mats[m];
#pragma unroll 2
        for (int k4 = 0; k4 < 16; k4++) {
            float tv[8][4];
#pragma unroll
            for (int i = 0; i < 8; i++) {
                int n = base + ng + 16 * i;
                n = (n < N_NODES) ? n : (N_NODES - 1);
                ushort4 t = T[(size_t)n * 16 + k4];
                tv[i][0] = bf2f(t.x); tv[i][1] = bf2f(t.y);
                tv[i][2] = bf2f(t.z); tv[i][3] = bf2f(t.w);
            }
#pragma unroll
            for (int kk = 0; kk < 4; kk++) {
                float4 w = Ws[((m + 1) * 64 + k4 * 4 + kk) * 16 + jg];
#pragma unroll
                for (int i = 0; i < 8; i++) {
                    acc[i].x += tv[i][kk] * w.x;
                    acc[i].y += tv[i][kk] * w.y;
                    acc[i].z += tv[i][kk] * w.z;
                    acc[i].w += tv[i][kk] * w.w;
                }
            }
        }
    }

    float4 bb = ((const float4*)b1)[jg];
#pragma unroll
    for (int i = 0; i < 8; i++) {
        int n = base + ng + 16 * i;
        if (n < N_NODES) {
            float4 v;
            v.x = fmaxf(acc[i].x + bb.x, 0.0f);
            v.y = fmaxf(acc[i].y + bb.y, 0.0f);
            v.z = fmaxf(acc[i].z + bb.z, 0.0f);
            v.w = fmaxf(acc[i].w + bb.w, 0.0f);
            ((float4*)(h + (size_t)n * 64))[jg] = v;
        }
    }
}

// ---------------- layer-2 projection: P,Q f32; Rs = dis*R in bf16 ----------------

__global__ __launch_bounds__(192) void proj_kernel(
    const float* __restrict__ h, const float* __restrict__ W2, const float* __restrict__ b2,
    const float* __restrict__ dis,
    float* __restrict__ P, float* __restrict__ Q, unsigned short* __restrict__ Rb) {

    __shared__ float4 Wp[64 * 12];  // [64 k][12 jg] float4 = 12 KB

    if (blockIdx.x == 0 && threadIdx.x < 8)  // Rs sentinel row N = 0
        ((unsigned int*)(Rb + ((size_t)N_NODES << 4)))[threadIdx.x] = 0u;

    const float4* Wg = (const float4*)W2;  // 768 float4; mat m at m*256
    for (int f = threadIdx.x; f < 768; f += 192) {
        int i = f / 12, g = f % 12;
        float4 v;
        if (g < 4) {
            float4 a = Wg[i * 4 + g], c = Wg[512 + i * 4 + g];
            v = make_float4(a.x - c.x, a.y - c.y, a.z - c.z, a.w - c.w);
        } else if (g < 8) {
            v = Wg[256 + i * 4 + (g - 4)];
        } else {
            v = Wg[512 + i * 4 + (g - 8)];
        }
        Wp[f] = v;
    }
    __syncthreads();

    const int jg = threadIdx.x % 12;
    const int ng = threadIdx.x / 12;  // 0..15
    const int base = blockIdx.x * GT_N;

    float4 acc[8];
#pragma unroll
    for (int i = 0; i < 8; i++) acc[i] = make_float4(0.f, 0.f, 0.f, 0.f);

    const float4* H = (const float4*)h;
#pragma unroll 2
    for (int k4 = 0; k4 < 16; k4++) {
        float tv[8][4];
#pragma unroll
        for (int i = 0; i < 8; i++) {
            int n = base + ng + 16 * i;
            n = (n < N_NODES) ? n : (N_NODES - 1);
            float4 t = H[(size_t)n * 16 + k4];
            tv[i][0] = t.x; tv[i][1] = t.y; tv[i][2] = t.z; tv[i][3] = t.w;
        }
#pragma unroll
        for (int kk = 0; kk < 4; kk++) {
            float4 w = Wp[(k4 * 4 + kk) * 12 + jg];
#pragma unroll
            for (int i = 0; i < 8; i++) {
                acc[i].x += tv[i][kk] * w.x;
                acc[i].y += tv[i][kk] * w.y;
                acc[i].z += tv[i][kk] * w.z;
                acc[i].w += tv[i][kk] * w.w;
            }
        }
    }

#pragma unroll
    for (int i = 0; i < 8; i++) {
        int n = base + ng + 16 * i;
        if (n >= N_NODES) continue;
        if (jg < 4) {
            float4 bv = ((const float4*)b2)[jg];
            float4 v = make_float4(acc[i].x + bv.x, acc[i].y + bv.y,
                                   acc[i].z + bv.z, acc[i].w + bv.w);
            ((float4*)(P + (size_t)n * 16))[jg] = v;
        } else if (jg < 8) {
            ((float4*)(Q + (size_t)n * 16))[jg - 4] =
                make_float4(acc[i].x, acc[i].y, acc[i].z, acc[i].w);
        } else {
            float d = dis[n];
            ushort4 v;
            v.x = f2bf(acc[i].x * d); v.y = f2bf(acc[i].y * d);
            v.z = f2bf(acc[i].z * d); v.w = f2bf(acc[i].w * d);
            *(ushort4*)(Rb + (size_t)n * 16 + (jg - 8) * 4) = v;
        }
    }
}

// ---------------- launch ----------------

extern "C" void kernel_launch(void* const* d_in, const int* in_sizes, int n_in,
                              void* d_out, int out_size, void* d_ws, size_t ws_size,
                              hipStream_t stream) {
    const float* x  = (const float*)d_in[0];
    const int* edge = (const int*)d_in[1];
    const float* W1 = (const float*)d_in[2];
    const float* b1 = (const float*)d_in[3];
    const float* W2 = (const float*)d_in[4];
    const float* b2 = (const float*)d_in[5];
    float* out = (float*)d_out;

    const int* row = edge;            // edge_index[0]
    const int* col = edge + E_EDGES;  // edge_index[1]

    // workspace layout
    char* ws = (char*)d_ws;
    size_t off = 0;
    auto alloc = [&](size_t bytes) {
        void* p = ws + off;
        off = (off + bytes + 255) & ~(size_t)255;
        return p;
    };
    unsigned int*   deg    = (unsigned int*)alloc(N_NODES * 4);
    float*          dis    = (float*)alloc(N_NODES * 4);
    unsigned int*   rowptr = (unsigned int*)alloc(N_NODES * 4);
    unsigned int*   cursor = (unsigned int*)alloc(N_NODES * 4);
    unsigned int*   bsum   = (unsigned int*)alloc(512 * 4);
    unsigned int*   ccol   = (unsigned int*)alloc((size_t)CSR_CAP * 4);
    unsigned short* xsB    = (unsigned short*)alloc((size_t)(N_NODES + 1) * 64 * 2);  // xs, then B
    unsigned short* As     = (unsigned short*)alloc((size_t)(N_NODES + 1) * 64 * 2);  // dis*A
    unsigned short* A      = (unsigned short*)alloc((size_t)(N_NODES + 1) * 64 * 2);  // unscaled
    float*          H      = (float*)alloc((size_t)N_NODES * 64 * 4);
    float*          P      = (float*)alloc((size_t)N_NODES * 16 * 4);
    float*          Q      = (float*)alloc((size_t)N_NODES * 16 * 4);
    unsigned short* Rs     = (unsigned short*)alloc((size_t)(N_NODES + 1) * 16 * 2);
    unsigned short* Ss     = (unsigned short*)alloc((size_t)(N_NODES + 1) * 16 * 2);

    const int nodeBlocks    = (N_NODES + 255) / 256;  // 391
    const int edgeBlocks    = (E_EDGES + 255) / 256;  // 6250
    const int spmm64Blocks  = (N_NODES + 4) / 4;      // covers sentinel wid==N
    const int spmm16aBlocks = (N_NODES + 16) / 16;    // covers sentinel
    const int spmm16bBlocks = (N_NODES + 15) / 16;
    const int convBlocks    = ((N_NODES + 1) * 16 + 255) / 256;
    const int gemmBlocks    = (N_NODES + GT_N - 1) / GT_N;  // 782
    const int fillBlocks    = 256 * FILL_G;           // 256 chunks x 8 groups

    // ---- build norm + padded CSR ----
    hipMemsetAsync(deg, 0, N_NODES * 4, stream);
    hipMemsetAsync(ccol, 0xFF, (size_t)CSR_CAP * 4, stream);  // pad sentinel
    deg_kernel<<<edgeBlocks, 256, 0, stream>>>(row, col, deg);
    scan1_kernel<<<nodeBlocks, 256, 0, stream>>>(deg, rowptr, bsum, dis);
    scan2_kernel<<<1, 512, 0, stream>>>(bsum, nodeBlocks);
    scan3_kernel<<<nodeBlocks, 256, 0, stream>>>(rowptr, bsum, cursor);
    fill_kernel<<<fillBlocks, 256, 0, stream>>>(row, col, cursor, (int*)ccol);
    conv_kernel<<<convBlocks, 256, 0, stream>>>(x, dis, xsB);

    // ---- layer 1 SpMMs: {As, A} = from xs; B = from As (B aliases dead xs) ----
    spmm64_kernel<true><<<spmm64Blocks, 256, 0, stream>>>(rowptr, deg, ccol, dis, xsB, As, A);
    spmm64_kernel<false><<<spmm64Blocks, 256, 0, stream>>>(rowptr, deg, ccol, dis, As, nullptr, xsB);

    // ---- GEMMs: H = relu(layer1); P,Q (f32), Rs = dis*R (bf16) ----
    gemm1_kernel<<<gemmBlocks, 256, 0, stream>>>(x, A, xsB, W1, b1, H);
    proj_kernel<<<gemmBlocks, 192, 0, stream>>>(H, W2, b2, dis, P, Q, Rs);

    // ---- layer 2 SpMMs: Ss = dis*(Q + 2*L(R)); out = P + L(S) ----
    spmm16_kernel<0><<<spmm16aBlocks, 256, 0, stream>>>(rowptr, deg, ccol, dis, Rs, Q, Ss, nullptr);
    spmm16_kernel<1><<<spmm16bBlocks, 256, 0, stream>>>(rowptr, deg, ccol, dis, Ss, P, nullptr, out);
}